// Round 11
// baseline (118.063 us; speedup 1.0000x reference)
//
#include <hip/hip_runtime.h>
#include <hip/hip_bf16.h>
#include <hip/hip_fp16.h>

#define BB 4
#define SS 2048
#define DD 512

typedef short s16x8 __attribute__((ext_vector_type(8)));
typedef short s16x4 __attribute__((ext_vector_type(4)));
typedef float f32x4 __attribute__((ext_vector_type(4)));
typedef _Float16 f16x8 __attribute__((ext_vector_type(8)));

__device__ __forceinline__ short f2h(float f) {
    const _Float16 h = (_Float16)f;
    union { _Float16 h; short s; } u; u.h = h; return u.s;
}
__device__ __forceinline__ float h2f(short s) {
    union { short s; _Float16 h; } u; u.s = s; return (float)u.h;
}
__device__ __forceinline__ f16x8 as_h(s16x8 v) {
    union { s16x8 s; f16x8 h; } u; u.s = v; return u.h;
}

__device__ __forceinline__ void gload_lds16(const void* g, void* l) {
    __builtin_amdgcn_global_load_lds(
        (const __attribute__((address_space(1))) void*)g,
        (__attribute__((address_space(3))) void*)l, 16, 0, 0);
}

// ---------------------------------------------------------------------------
// QK^T 256x256, BK=32, 8 waves, single-pass fp16, XCD swizzle.
// 2-phase/tile schedule (16 MFMA per barrier-pair, 4 barriers/tile):
//  A: read A rows0-3 | issue k,q (pinned) | bar | lgkm(0) | MFMA | vmcnt(2) | bar
//  B: read A rows4-7 | read B-next        | bar | lgkm(4) | MFMA | vmcnt(0) | bar
// Handshakes identical to the R9-proven 4-phase version, just merged.
// int16 score out (scale 128) via LDS repack.
// ---------------------------------------------------------------------------
__global__ __launch_bounds__(512, 2) void qkt256(
    const short* __restrict__ qf, const short* __restrict__ kf,
    short* __restrict__ outS, int nwg)
{
    __shared__ short lds[65536];  // 128 KiB (epilogue repack needs all of it)

    const int tid = threadIdx.x;
    const int wave = tid >> 6, lane = tid & 63;
    const int flat = blockIdx.x + 8 * blockIdx.y + 64 * blockIdx.z;
    const int w = (flat & 7) * (nwg >> 3) + (flat >> 3);
    const int bm = ((w >> 3) & 7) * 256, bn = (w & 7) * 256;
    const long z = w >> 6;
    qf += z * (long)SS * DD; kf += z * (long)SS * DD;
    outS += z * (long)SS * SS;

    const int wm = (wave >> 2) * 128, wn = (wave & 3) * 64;
    const int lrow = lane & 15, lk16 = (lane >> 4) * 16;

    f32x4 acc[8][4] = {};

    auto base = [&](int buf, int arr) -> short* { return &lds[(buf * 2 + arr) * 8192]; };
    auto issue = [&](int buf, int arr, int k0) {
#pragma unroll
        for (int h = 0; h < 2; h++) {
            const int Lb = (h << 13) + (wave << 10) + (lane << 4);
            const int Ls = Lb ^ (((Lb >> 7) & 3) << 4);
            const int row = Ls >> 6, elem = (Ls & 63) >> 1;
            const short* s = arr ? kf : qf;
            const int rb = arr ? bn : bm;
            gload_lds16(s + (size_t)(rb + row) * DD + k0 + elem,
                        (char*)base(buf, arr) + Lb);
        }
    };
    auto rd = [&](int buf, int arr, int row) -> s16x8 {
        const int L = (row << 6) + lk16;
        const int Ls = L ^ (((L >> 7) & 3) << 4);
        return *(const s16x8*)((const char*)base(buf, arr) + Ls);
    };

#define QK_TILE(T, CUR, Bc, Bn, PREF)                                            \
  {                                                                              \
    /* ---- phase A: acc rows 0-3 ---- */                                        \
    s16x8 aA0 = rd(CUR, 0, wm + 0 * 16 + lrow);                                  \
    s16x8 aA1 = rd(CUR, 0, wm + 1 * 16 + lrow);                                  \
    s16x8 aA2 = rd(CUR, 0, wm + 2 * 16 + lrow);                                  \
    s16x8 aA3 = rd(CUR, 0, wm + 3 * 16 + lrow);                                  \
    if (PREF) {                                                                  \
      issue((CUR) ^ 1, 1, ((T) + 1) * 32);   /* k first */                       \
      __builtin_amdgcn_sched_barrier(0);                                         \
      issue((CUR) ^ 1, 0, ((T) + 1) * 32);   /* q second */                      \
    }                                                                            \
    __builtin_amdgcn_s_barrier();                                                \
    asm volatile("s_waitcnt lgkmcnt(0)" ::: "memory");                           \
    __builtin_amdgcn_sched_barrier(0);                                           \
    __builtin_amdgcn_s_setprio(1);                                               \
    {                                                                            \
      _Pragma("unroll")                                                          \
      for (int n = 0; n < 4; n++) {                                              \
        acc[0][n] = __builtin_amdgcn_mfma_f32_16x16x32_f16(as_h(aA0), as_h(Bc[n]), acc[0][n], 0, 0, 0); \
        acc[1][n] = __builtin_amdgcn_mfma_f32_16x16x32_f16(as_h(aA1), as_h(Bc[n]), acc[1][n], 0, 0, 0); \
        acc[2][n] = __builtin_amdgcn_mfma_f32_16x16x32_f16(as_h(aA2), as_h(Bc[n]), acc[2][n], 0, 0, 0); \
        acc[3][n] = __builtin_amdgcn_mfma_f32_16x16x32_f16(as_h(aA3), as_h(Bc[n]), acc[3][n], 0, 0, 0); \
      }                                                                          \
    }                                                                            \
    __builtin_amdgcn_s_setprio(0);                                               \
    if (PREF) { asm volatile("s_waitcnt vmcnt(2)" ::: "memory");                 \
                __builtin_amdgcn_sched_barrier(0); }                             \
    __builtin_amdgcn_s_barrier();                                                \
    /* ---- phase B: acc rows 4-7 ---- */                                        \
    aA0 = rd(CUR, 0, wm + 4 * 16 + lrow);                                        \
    aA1 = rd(CUR, 0, wm + 5 * 16 + lrow);                                        \
    aA2 = rd(CUR, 0, wm + 6 * 16 + lrow);                                        \
    aA3 = rd(CUR, 0, wm + 7 * 16 + lrow);                                        \
    if (PREF) {                                                                  \
      __builtin_amdgcn_sched_barrier(0); /* pin A-reads before B-next reads */   \
      _Pragma("unroll")                                                          \
      for (int n = 0; n < 4; n++) {                                              \
        Bn[n] = rd((CUR) ^ 1, 1, wn + n * 16 + lrow);                            \
      }                                                                          \
    }                                                                            \
    __builtin_amdgcn_s_barrier();                                                \
    if (PREF) { asm volatile("s_waitcnt lgkmcnt(4)" ::: "memory"); }             \
    else      { asm volatile("s_waitcnt lgkmcnt(0)" ::: "memory"); }             \
    __builtin_amdgcn_sched_barrier(0);                                           \
    __builtin_amdgcn_s_setprio(1);                                               \
    {                                                                            \
      _Pragma("unroll")                                                          \
      for (int n = 0; n < 4; n++) {                                              \
        acc[4][n] = __builtin_amdgcn_mfma_f32_16x16x32_f16(as_h(aA0), as_h(Bc[n]), acc[4][n], 0, 0, 0); \
        acc[5][n] = __builtin_amdgcn_mfma_f32_16x16x32_f16(as_h(aA1), as_h(Bc[n]), acc[5][n], 0, 0, 0); \
        acc[6][n] = __builtin_amdgcn_mfma_f32_16x16x32_f16(as_h(aA2), as_h(Bc[n]), acc[6][n], 0, 0, 0); \
        acc[7][n] = __builtin_amdgcn_mfma_f32_16x16x32_f16(as_h(aA3), as_h(Bc[n]), acc[7][n], 0, 0, 0); \
      }                                                                          \
    }                                                                            \
    __builtin_amdgcn_s_setprio(0);                                               \
    if (PREF) { asm volatile("s_waitcnt vmcnt(0)" ::: "memory");                 \
                __builtin_amdgcn_sched_barrier(0); }                             \
    __builtin_amdgcn_s_barrier();                                                \
  }

    issue(0, 1, 0); issue(0, 0, 0);
    asm volatile("s_waitcnt vmcnt(0)" ::: "memory");
    __builtin_amdgcn_s_barrier();
    s16x8 bE[4], bO[4];
#pragma unroll
    for (int n = 0; n < 4; n++) bE[n] = rd(0, 1, wn + n * 16 + lrow);

    for (int t = 0; t < 14; t += 2) {
        QK_TILE(t,     0, bE, bO, 1);
        QK_TILE(t + 1, 1, bO, bE, 1);
    }
    QK_TILE(14, 0, bE, bO, 1);
    QK_TILE(15, 1, bO, bE, 0);
#undef QK_TILE

    __syncthreads();
    short* ebuf = &lds[0];  // 128 KiB = [256][256] int16
#pragma unroll
    for (int m = 0; m < 8; m++) {
#pragma unroll
        for (int n = 0; n < 4; n++) {
#pragma unroll
            for (int j = 0; j < 4; j++) {
                const int rl = wm + m * 16 + (lane >> 4) * 4 + j;
                const int cl = wn + n * 16 + lrow;
                const int pcb = (cl >> 3) ^ ((rl & 3) << 1);
                ebuf[rl * 256 + pcb * 8 + (cl & 7)] =
                    (short)__float2int_rn(acc[m][n][j] * 128.0f);
            }
        }
    }
    __syncthreads();
#pragma unroll
    for (int it = 0; it < 16; it++) {
        const int u = it * 512 + tid;
        const int R = u >> 5, cb = u & 31;
        const int pcb = cb ^ ((R & 3) << 1);
        const s16x8 val = *(const s16x8*)&ebuf[R * 256 + pcb * 8];
        *(s16x8*)&outS[(size_t)(bm + R) * SS + bn + cb * 8] = val;
    }
}

// ---------------------------------------------------------------------------
// Unified projection, all-fp16 (R10-proven): grid dim3(12, 64).
// wsel 0=Q, 1=K (2-pass xh*W + xl*W), 2=V (1-pass, transposed fp16 Vt out).
// LDS 48 KiB -> 3 blocks/CU. 3-bit XOR swizzle. Coalesced epilogue via cbuf.
// ---------------------------------------------------------------------------
__global__ __launch_bounds__(256, 3) void proj_all(
    const short* __restrict__ xh, const short* __restrict__ xl,
    const short* __restrict__ wt,
    const float* __restrict__ bq, const float* __restrict__ bk,
    const float* __restrict__ bv,
    short* __restrict__ qfp, short* __restrict__ kfp, short* __restrict__ vt)
{
    __shared__ short As[2][128 * 64];   // 32 KiB, reused as cbuf
    __shared__ short Bs[128 * 64];      // 16 KiB

    const int tid = threadIdx.x;
    const int wave = tid >> 6, lane = tid & 63;
    const int wsel = blockIdx.x >> 2;
    const int bnl = (blockIdx.x & 3) * 128;
    const int bm = blockIdx.y * 128;
    const bool lo = (wsel < 2);
    const short* B0 = wt + (size_t)wsel * DD * DD;
    const float* bias = (wsel == 0) ? bq : (wsel == 1) ? bk : bv;

    f32x4 acc[4][4] = {};
    const int wm = (wave >> 1) * 64, wn = (wave & 1) * 64;
    const int lrow = lane & 15, lk = (lane >> 4) * 8;

    auto swz = [](int L) { return L ^ (((L >> 7) & 7) << 4); };

    for (int k0 = 0; k0 < DD; k0 += 64) {
        if (k0) __syncthreads();
#pragma unroll
        for (int r = 0; r < 4; r++) {
            const int L = tid * 16 + r * 4096;
            const int Ls = swz(L);
            const int row = Ls >> 7, col = (Ls & 127) >> 1;
            gload_lds16(xh + (size_t)(bm + row) * DD + k0 + col, (char*)&As[0][0] + L);
            gload_lds16(B0 + (size_t)(bnl + row) * DD + k0 + col, (char*)&Bs[0] + L);
            if (lo)
                gload_lds16(xl + (size_t)(bm + row) * DD + k0 + col, (char*)&As[1][0] + L);
        }
        __syncthreads();

#pragma unroll
        for (int kk = 0; kk < 64; kk += 32) {
            s16x8 ah[4], bh[4], al[4];
#pragma unroll
            for (int m = 0; m < 4; m++)
                ah[m] = *(const s16x8*)((const char*)&As[0][0] +
                        swz(((wm + m * 16 + lrow) * 64 + kk + lk) * 2));
#pragma unroll
            for (int n = 0; n < 4; n++)
                bh[n] = *(const s16x8*)((const char*)&Bs[0] +
                        swz(((wn + n * 16 + lrow) * 64 + kk + lk) * 2));
            if (lo) {
#pragma unroll
                for (int m = 0; m < 4; m++)
                    al[m] = *(const s16x8*)((const char*)&As[1][0] +
                            swz(((wm + m * 16 + lrow) * 64 + kk + lk) * 2));
            }
#pragma unroll
            for (int m = 0; m < 4; m++) {
#pragma unroll
                for (int n = 0; n < 4; n++) {
                    acc[m][n] = __builtin_amdgcn_mfma_f32_16x16x32_f16(
                        as_h(ah[m]), as_h(bh[n]), acc[m][n], 0, 0, 0);
                    if (lo)
                        acc[m][n] = __builtin_amdgcn_mfma_f32_16x16x32_f16(
                            as_h(al[m]), as_h(bh[n]), acc[m][n], 0, 0, 0);
                }
            }
        }
    }

    __syncthreads();
    short* cbuf = &As[0][0];  // 32 KiB = 128*128 shorts
#pragma unroll
    for (int m = 0; m < 4; m++) {
#pragma unroll
        for (int n = 0; n < 4; n++) {
#pragma unroll
            for (int j = 0; j < 4; j++) {
                const int rl = wm + m * 16 + (lane >> 4) * 4 + j;
                const int cl = wn + n * 16 + lrow;
                const float v = acc[m][n][j] + bias[bnl + cl];
                if (wsel < 2)
                    cbuf[rl * 128 + (cl ^ ((rl & 7) << 3))] = f2h(v);
                else
                    cbuf[cl * 128 + (rl ^ ((cl & 7) << 3))] = f2h(v);
            }
        }
    }
    __syncthreads();
    if (wsel < 2) {
        short* outp = wsel ? kfp : qfp;
#pragma unroll
        for (int it = 0; it < 8; it++) {
            const int u = it * 256 + tid;
            const int r = u >> 4, c8 = (u & 15) * 8;
            const s16x8 val = *(const s16x8*)&cbuf[r * 128 + (c8 ^ ((r & 7) << 3))];
            *(s16x8*)&outp[(size_t)(bm + r) * DD + bnl + c8] = val;
        }
    } else {
        const int b = bm >> 11, s0 = bm & 2047;
#pragma unroll
        for (int it = 0; it < 8; it++) {
            const int idx = it * 256 + tid;
            const int dd = idx >> 4, c8 = (idx & 15) * 8;
            const s16x8 val = *(const s16x8*)&cbuf[dd * 128 + (c8 ^ ((dd & 7) << 3))];
            *(s16x8*)&vt[((size_t)b << 20) + ((size_t)(bnl + dd) << 11) + s0 + c8] = val;
        }
    }
}

// ---------------------------------------------------------------------------
// PV GEMM fp16: 64x128 tile (2+ blocks/CU), 3-bit XOR swizzle (R8-proven).
// ---------------------------------------------------------------------------
__global__ __launch_bounds__(256, 2) void pv_gemm(
    const short* __restrict__ P, const short* __restrict__ vt,
    float* __restrict__ out)
{
    __shared__ short As[64 * 64];    // 8 KiB
    __shared__ short Bs[128 * 64];   // 16 KiB

    const int tid = threadIdx.x;
    const int wave = tid >> 6, lane = tid & 63;
    const int bm = blockIdx.y * 64, bn = blockIdx.x * 128;
    const long z = blockIdx.z;
    P += z * (long)SS * SS;
    vt += z << 20;
    out += z * (long)SS * DD;

    f32x4 acc[2][4] = {};
    const int wm = (wave >> 1) * 32, wn = (wave & 1) * 64;
    const int lrow = lane & 15, lk = (lane >> 4) * 8;

    auto swz = [](int L) { return L ^ (((L >> 7) & 7) << 4); };

    for (int k0 = 0; k0 < SS; k0 += 64) {
        if (k0) __syncthreads();
#pragma unroll
        for (int r = 0; r < 2; r++) {
            const int L = tid * 16 + r * 4096;
            const int Ls = swz(L);
            const int row = Ls >> 7, col = (Ls & 127) >> 1;
            gload_lds16(P + (size_t)(bm + row) * SS + k0 + col, (char*)&As[0] + L);
        }
#pragma unroll
        for (int r = 0; r < 4; r++) {
            const int L = tid * 16 + r * 4096;
            const int Ls = swz(L);
            const int row = Ls >> 7, col = (Ls & 127) >> 1;
            gload_lds16(vt + ((size_t)(bn + row) << 11) + k0 + col, (char*)&Bs[0] + L);
        }
        __syncthreads();

#pragma unroll
        for (int kk = 0; kk < 64; kk += 32) {
            s16x8 a[2], b[4];
#pragma unroll
            for (int m = 0; m < 2; m++)
                a[m] = *(const s16x8*)((const char*)&As[0] +
                       swz(((wm + m * 16 + lrow) * 64 + kk + lk) * 2));
#pragma unroll
            for (int n = 0; n < 4; n++)
                b[n] = *(const s16x8*)((const char*)&Bs[0] +
                       swz(((wn + n * 16 + lrow) * 64 + kk + lk) * 2));
#pragma unroll
            for (int m = 0; m < 2; m++)
#pragma unroll
                for (int n = 0; n < 4; n++)
                    acc[m][n] = __builtin_amdgcn_mfma_f32_16x16x32_f16(
                        as_h(a[m]), as_h(b[n]), acc[m][n], 0, 0, 0);
        }
    }

#pragma unroll
    for (int m = 0; m < 2; m++) {
#pragma unroll
        for (int n = 0; n < 4; n++) {
#pragma unroll
            for (int j = 0; j < 4; j++) {
                const int row = bm + wm + m * 16 + (lane >> 4) * 4 + j;
                const int col = bn + wn + n * 16 + lrow;
                out[(size_t)row * DD + col] = acc[m][n][j];
            }
        }
    }
}

// merged casts: blocks [0,4096) split x into fp16 hi/lo;
// [4096,7168) transpose W into single fp16 plane.
__global__ __launch_bounds__(256) void cast_all(
    const float* __restrict__ x,
    const float* __restrict__ wq, const float* __restrict__ wk,
    const float* __restrict__ wv,
    short* __restrict__ xh, short* __restrict__ xl,
    short* __restrict__ wt)
{
    const int bid = blockIdx.x;
    if (bid < 4096) {
        const int i = bid * 256 + threadIdx.x;
        const float4 v = ((const float4*)x)[i];
        const float vv[4] = {v.x, v.y, v.z, v.w};
        s16x4 h, l;
#pragma unroll
        for (int j = 0; j < 4; j++) {
            const short hh = f2h(vv[j]);
            h[j] = hh;
            l[j] = f2h(vv[j] - h2f(hh));
        }
        ((s16x4*)xh)[i] = h;
        ((s16x4*)xl)[i] = l;
    } else {
        const int t = (bid - 4096) * 256 + threadIdx.x;
        const int w = t >> 18;
        const int r = t & 262143;
        const float* src = (w == 0) ? wq : ((w == 1) ? wk : wv);
        const float v = src[r];
        const int k = r >> 9, n = r & 511;
        wt[((size_t)w << 18) + ((size_t)n << 9) + k] = f2h(v);
    }
}

// softmax over int16 scores (scale 1/128), fp16 P out
__global__ __launch_bounds__(256) void softmax_rows(
    const short* __restrict__ S, short* __restrict__ P)
{
    const int row = blockIdx.x;
    const long z = blockIdx.y;
    const short* s = S + z * (long)SS * SS + (long)row * SS;
    short* p = P + z * (long)SS * SS + (long)row * SS;
    const int tid = threadIdx.x;

    const s16x8 raw = ((const s16x8*)s)[tid];
    float v[8];
#pragma unroll
    for (int j = 0; j < 8; j++) v[j] = (float)(int)raw[j] * 0.0078125f;

    float m = v[0];
#pragma unroll
    for (int j = 1; j < 8; j++) m = fmaxf(m, v[j]);
#pragma unroll
    for (int off = 32; off >= 1; off >>= 1) m = fmaxf(m, __shfl_xor(m, off));
    __shared__ float redm[4], reds[4];
    if ((tid & 63) == 0) redm[tid >> 6] = m;
    __syncthreads();
    m = fmaxf(fmaxf(redm[0], redm[1]), fmaxf(redm[2], redm[3]));

    float e[8], sum = 0.f;
#pragma unroll
    for (int j = 0; j < 8; j++) { e[j] = __expf(v[j] - m); sum += e[j]; }
#pragma unroll
    for (int off = 32; off >= 1; off >>= 1) sum += __shfl_xor(sum, off);
    if ((tid & 63) == 0) reds[tid >> 6] = sum;
    __syncthreads();
    sum = reds[0] + reds[1] + reds[2] + reds[3];
    const float inv = 1.0f / sum;

    s16x8 o;
#pragma unroll
    for (int j = 0; j < 8; j++) o[j] = f2h(e[j] * inv);
    ((s16x8*)p)[tid] = o;
}

extern "C" void kernel_launch(void* const* d_in, const int* in_sizes, int n_in,
                              void* d_out, int out_size, void* d_ws, size_t ws_size,
                              hipStream_t stream)
{
    const float* x  = (const float*)d_in[0];
    const float* Wq = (const float*)d_in[1];
    const float* Wk = (const float*)d_in[2];
    const float* Wv = (const float*)d_in[3];
    const float* bq = (const float*)d_in[4];
    const float* bk = (const float*)d_in[5];
    const float* bv = (const float*)d_in[6];
    float* out = (float*)d_out;

    const size_t MK = (size_t)BB * SS * DD;
    char* ws = (char*)d_ws;
    short* xh  = (short*)ws; ws += MK * 2;
    short* xl  = (short*)ws; ws += MK * 2;
    short* wt  = (short*)ws; ws += 3ull * DD * DD * 2;
    short* qfp = (short*)ws; ws += MK * 2;
    short* kfp = (short*)ws; ws += MK * 2;
    short* vt  = (short*)ws; ws += MK * 2;
    const size_t fixed = (size_t)(ws - (char*)d_ws);

    int g = 4;
    while (g > 0 && fixed + (size_t)g * ((size_t)SS * SS * 2 + (size_t)SS * SS * 2) > ws_size)
        g >>= 1;
    if (g == 0) return;
    short* sc = (short*)ws;
    short* P  = (short*)(ws + (size_t)g * SS * SS * 2);

    cast_all<<<dim3(7168), 256, 0, stream>>>(x, Wq, Wk, Wv, xh, xl, wt);
    proj_all<<<dim3(12, 64), 256, 0, stream>>>(xh, xl, wt, bq, bk, bv,
                                               qfp, kfp, vt);

    for (int b0 = 0; b0 < BB; b0 += g) {
        const int gg = (b0 + g <= BB) ? g : (BB - b0);
        qkt256<<<dim3(8, 8, gg), 512, 0, stream>>>(
            qfp + (size_t)b0 * SS * DD, kfp + (size_t)b0 * SS * DD, sc, 64 * gg);
        softmax_rows<<<dim3(SS, gg), 256, 0, stream>>>(sc, P);
        pv_gemm<<<dim3(4, 32, gg), 256, 0, stream>>>(
            P, vt + ((size_t)b0 << 20), out + (size_t)b0 * SS * DD);
    }
}

// Round 12
// 116.515 us; speedup vs baseline: 1.0133x; 1.0133x over previous
//
#include <hip/hip_runtime.h>
#include <hip/hip_bf16.h>
#include <hip/hip_fp16.h>

#define BB 4
#define SS 2048
#define DD 512

typedef short s16x8 __attribute__((ext_vector_type(8)));
typedef short s16x4 __attribute__((ext_vector_type(4)));
typedef float f32x4 __attribute__((ext_vector_type(4)));
typedef _Float16 f16x8 __attribute__((ext_vector_type(8)));

__device__ __forceinline__ short f2h(float f) {
    const _Float16 h = (_Float16)f;
    union { _Float16 h; short s; } u; u.h = h; return u.s;
}
__device__ __forceinline__ float h2f(short s) {
    union { short s; _Float16 h; } u; u.s = s; return (float)u.h;
}
__device__ __forceinline__ f16x8 as_h(s16x8 v) {
    union { s16x8 s; f16x8 h; } u; u.s = v; return u.h;
}

__device__ __forceinline__ void gload_lds16(const void* g, void* l) {
    __builtin_amdgcn_global_load_lds(
        (const __attribute__((address_space(1))) void*)g,
        (__attribute__((address_space(3))) void*)l, 16, 0, 0);
}

#define SB0 __builtin_amdgcn_sched_barrier(0)
#define LGKM0 asm volatile("s_waitcnt lgkmcnt(0)" ::: "memory")
#define VM0   asm volatile("s_waitcnt vmcnt(0)" ::: "memory")

// ---------------------------------------------------------------------------
// QK^T 256x256, BK=32, 8 waves, fp16, XCD swizzle. Single-phase-per-tile
// T3 recipe: read 12 frags | issue 4 gloads (t+1, dbuf) | lgkm(0) | 32 MFMA
// | vmcnt(0) | ONE barrier. int16 scores (scale 128) via LDS repack.
// ---------------------------------------------------------------------------
__global__ __launch_bounds__(512, 2) void qkt256(
    const short* __restrict__ qf, const short* __restrict__ kf,
    short* __restrict__ outS, int nwg)
{
    __shared__ short lds[65536];  // 64 KiB staging + full 128 KiB for repack

    const int tid = threadIdx.x;
    const int wave = tid >> 6, lane = tid & 63;
    const int flat = blockIdx.x + 8 * blockIdx.y + 64 * blockIdx.z;
    const int w = (flat & 7) * (nwg >> 3) + (flat >> 3);
    const int bm = ((w >> 3) & 7) * 256, bn = (w & 7) * 256;
    const long z = w >> 6;
    qf += z * (long)SS * DD; kf += z * (long)SS * DD;
    outS += z * (long)SS * SS;

    const int wm = (wave >> 2) * 128, wn = (wave & 3) * 64;
    const int lrow = lane & 15, lk16 = (lane >> 4) * 16;

    f32x4 acc[8][4] = {};

    auto base = [&](int buf, int arr) -> short* { return &lds[(buf * 2 + arr) * 8192]; };
    auto issue = [&](int buf, int arr, int k0) {
#pragma unroll
        for (int h = 0; h < 2; h++) {
            const int Lb = (h << 13) + (tid << 4);
            const int Ls = Lb ^ (((Lb >> 7) & 3) << 4);
            const int row = Ls >> 6, elem = (Ls & 63) >> 1;
            const short* s = arr ? kf : qf;
            const int rb = arr ? bn : bm;
            gload_lds16(s + (size_t)(rb + row) * DD + k0 + elem,
                        (char*)base(buf, arr) + Lb);
        }
    };
    auto rd = [&](int buf, int arr, int row) -> s16x8 {
        const int L = (row << 6) + lk16;
        const int Ls = L ^ (((L >> 7) & 3) << 4);
        return *(const s16x8*)((const char*)base(buf, arr) + Ls);
    };

#define QK_TILE(T, CUR, PREF)                                                    \
  {                                                                              \
    s16x8 a[8], b[4];                                                            \
    _Pragma("unroll")                                                            \
    for (int m = 0; m < 8; m++) a[m] = rd(CUR, 0, wm + m * 16 + lrow);           \
    _Pragma("unroll")                                                            \
    for (int n = 0; n < 4; n++) b[n] = rd(CUR, 1, wn + n * 16 + lrow);           \
    if (PREF) { issue((CUR) ^ 1, 1, ((T) + 1) * 32); SB0;                        \
                issue((CUR) ^ 1, 0, ((T) + 1) * 32); }                           \
    LGKM0; SB0;                                                                  \
    __builtin_amdgcn_s_setprio(1);                                               \
    _Pragma("unroll")                                                            \
    for (int m = 0; m < 8; m++) {                                                \
      _Pragma("unroll")                                                          \
      for (int n = 0; n < 4; n++)                                                \
        acc[m][n] = __builtin_amdgcn_mfma_f32_16x16x32_f16(                      \
            as_h(a[m]), as_h(b[n]), acc[m][n], 0, 0, 0);                         \
    }                                                                            \
    __builtin_amdgcn_s_setprio(0);                                               \
    if (PREF) { VM0; SB0; }                                                      \
    __builtin_amdgcn_s_barrier();                                                \
  }

    issue(0, 1, 0); issue(0, 0, 0);
    VM0;
    __builtin_amdgcn_s_barrier();

    for (int t = 0; t < 16; t += 2) {
        QK_TILE(t,     0, 1);
        QK_TILE(t + 1, 1, (t + 1) < 15);
    }
#undef QK_TILE

    __syncthreads();
    short* ebuf = &lds[0];  // 128 KiB = [256][256] int16
#pragma unroll
    for (int m = 0; m < 8; m++) {
#pragma unroll
        for (int n = 0; n < 4; n++) {
#pragma unroll
            for (int j = 0; j < 4; j++) {
                const int rl = wm + m * 16 + (lane >> 4) * 4 + j;
                const int cl = wn + n * 16 + lrow;
                const int pcb = (cl >> 3) ^ ((rl & 3) << 1);
                ebuf[rl * 256 + pcb * 8 + (cl & 7)] =
                    (short)__float2int_rn(acc[m][n][j] * 128.0f);
            }
        }
    }
    __syncthreads();
#pragma unroll
    for (int it = 0; it < 16; it++) {
        const int u = it * 512 + tid;
        const int R = u >> 5, cb = u & 31;
        const int pcb = cb ^ ((R & 3) << 1);
        const s16x8 val = *(const s16x8*)&ebuf[R * 256 + pcb * 8];
        *(s16x8*)&outS[(size_t)(bm + R) * SS + bn + cb * 8] = val;
    }
}

// ---------------------------------------------------------------------------
// Unified projection, all-fp16, single-phase-per-tile T3 recipe.
// BK=32, dbuf, 3 planes {xh, xl, W} (V skips xl) = 48 KiB -> 3 blocks/CU.
// wsel 0=Q, 1=K (2-pass), 2=V (1-pass, transposed Vt out). Grid dim3(12,64).
// ---------------------------------------------------------------------------
__global__ __launch_bounds__(256, 3) void proj_all(
    const short* __restrict__ xh, const short* __restrict__ xl,
    const short* __restrict__ wt,
    const float* __restrict__ bq, const float* __restrict__ bk,
    const float* __restrict__ bv,
    short* __restrict__ qfp, short* __restrict__ kfp, short* __restrict__ vt)
{
    __shared__ short lds[24576];  // [2 buf][3 arr][4096] = 48 KiB; cbuf reuse

    const int tid = threadIdx.x;
    const int wave = tid >> 6, lane = tid & 63;
    const int wsel = blockIdx.x >> 2;
    const int bnl = (blockIdx.x & 3) * 128;
    const int bm = blockIdx.y * 128;
    const bool lo = (wsel < 2);
    const short* B0 = wt + (size_t)wsel * DD * DD;
    const float* bias = (wsel == 0) ? bq : (wsel == 1) ? bk : bv;

    f32x4 acc[4][4] = {};
    const int wm = (wave >> 1) * 64, wn = (wave & 1) * 64;
    const int lrow = lane & 15, lk16 = (lane >> 4) * 16;

    auto base = [&](int buf, int arr) -> short* { return &lds[(buf * 3 + arr) * 4096]; };
    auto issue = [&](int buf, int arr, int k0) {
#pragma unroll
        for (int h = 0; h < 2; h++) {
            const int Lb = (h << 12) + (tid << 4);
            const int Ls = Lb ^ (((Lb >> 7) & 3) << 4);
            const int row = Ls >> 6, elem = (Ls & 63) >> 1;
            const short* s = (arr == 0) ? xh : (arr == 1) ? xl : B0;
            const int rb = (arr < 2) ? bm : bnl;
            gload_lds16(s + (size_t)(rb + row) * DD + k0 + elem,
                        (char*)base(buf, arr) + Lb);
        }
    };
    auto rd = [&](int buf, int arr, int row) -> s16x8 {
        const int L = (row << 6) + lk16;
        const int Ls = L ^ (((L >> 7) & 3) << 4);
        return *(const s16x8*)((const char*)base(buf, arr) + Ls);
    };

#define PJ_TILE(T, CUR, PREF)                                                    \
  {                                                                              \
    s16x8 ah[4], al[4], b[4];                                                    \
    _Pragma("unroll")                                                            \
    for (int m = 0; m < 4; m++) ah[m] = rd(CUR, 0, wm + m * 16 + lrow);          \
    if (lo) {                                                                    \
      _Pragma("unroll")                                                          \
      for (int m = 0; m < 4; m++) al[m] = rd(CUR, 1, wm + m * 16 + lrow);        \
    }                                                                            \
    _Pragma("unroll")                                                            \
    for (int n = 0; n < 4; n++) b[n] = rd(CUR, 2, wn + n * 16 + lrow);           \
    if (PREF) {                                                                  \
      issue((CUR) ^ 1, 2, ((T) + 1) * 32); SB0;                                  \
      issue((CUR) ^ 1, 0, ((T) + 1) * 32);                                       \
      if (lo) issue((CUR) ^ 1, 1, ((T) + 1) * 32);                               \
    }                                                                            \
    LGKM0; SB0;                                                                  \
    __builtin_amdgcn_s_setprio(1);                                               \
    _Pragma("unroll")                                                            \
    for (int m = 0; m < 4; m++) {                                                \
      _Pragma("unroll")                                                          \
      for (int n = 0; n < 4; n++) {                                              \
        acc[m][n] = __builtin_amdgcn_mfma_f32_16x16x32_f16(                      \
            as_h(ah[m]), as_h(b[n]), acc[m][n], 0, 0, 0);                        \
        if (lo)                                                                  \
          acc[m][n] = __builtin_amdgcn_mfma_f32_16x16x32_f16(                    \
              as_h(al[m]), as_h(b[n]), acc[m][n], 0, 0, 0);                      \
      }                                                                          \
    }                                                                            \
    __builtin_amdgcn_s_setprio(0);                                               \
    if (PREF) { VM0; SB0; }                                                      \
    __builtin_amdgcn_s_barrier();                                                \
  }

    issue(0, 2, 0); issue(0, 0, 0);
    if (lo) issue(0, 1, 0);
    VM0;
    __builtin_amdgcn_s_barrier();

    for (int t = 0; t < 16; t += 2) {
        PJ_TILE(t,     0, 1);
        PJ_TILE(t + 1, 1, (t + 1) < 15);
    }
#undef PJ_TILE

    __syncthreads();
    short* cbuf = &lds[0];  // 32 KiB = 128*128 shorts
#pragma unroll
    for (int m = 0; m < 4; m++) {
#pragma unroll
        for (int n = 0; n < 4; n++) {
#pragma unroll
            for (int j = 0; j < 4; j++) {
                const int rl = wm + m * 16 + (lane >> 4) * 4 + j;
                const int cl = wn + n * 16 + lrow;
                const float v = acc[m][n][j] + bias[bnl + cl];
                if (wsel < 2)
                    cbuf[rl * 128 + (cl ^ ((rl & 7) << 3))] = f2h(v);
                else
                    cbuf[cl * 128 + (rl ^ ((cl & 7) << 3))] = f2h(v);
            }
        }
    }
    __syncthreads();
    if (wsel < 2) {
        short* outp = wsel ? kfp : qfp;
#pragma unroll
        for (int it = 0; it < 8; it++) {
            const int u = it * 256 + tid;
            const int r = u >> 4, c8 = (u & 15) * 8;
            const s16x8 val = *(const s16x8*)&cbuf[r * 128 + (c8 ^ ((r & 7) << 3))];
            *(s16x8*)&outp[(size_t)(bm + r) * DD + bnl + c8] = val;
        }
    } else {
        const int b = bm >> 11, s0 = bm & 2047;
#pragma unroll
        for (int it = 0; it < 8; it++) {
            const int idx = it * 256 + tid;
            const int dd = idx >> 4, c8 = (idx & 15) * 8;
            const s16x8 val = *(const s16x8*)&cbuf[dd * 128 + (c8 ^ ((dd & 7) << 3))];
            *(s16x8*)&vt[((size_t)b << 20) + ((size_t)(bnl + dd) << 11) + s0 + c8] = val;
        }
    }
}

// ---------------------------------------------------------------------------
// PV GEMM fp16: 64x128 tile, BK=64 dbuf (48 KiB -> 3 blocks/CU),
// single-phase-per-tile T3 recipe, 3-bit XOR swizzle (128-B rows).
// ---------------------------------------------------------------------------
__global__ __launch_bounds__(256, 3) void pv_gemm(
    const short* __restrict__ P, const short* __restrict__ vt,
    float* __restrict__ out)
{
    __shared__ short As[2][64 * 64];    // 8 KiB each
    __shared__ short Bs[2][128 * 64];   // 16 KiB each

    const int tid = threadIdx.x;
    const int wave = tid >> 6, lane = tid & 63;
    const int bm = blockIdx.y * 64, bn = blockIdx.x * 128;
    const long z = blockIdx.z;
    P += z * (long)SS * SS;
    vt += z << 20;
    out += z * (long)SS * DD;

    f32x4 acc[2][4] = {};
    const int wm = (wave >> 1) * 32, wn = (wave & 1) * 64;
    const int lrow = lane & 15, lk = (lane >> 4) * 8;

    auto swz = [](int L) { return L ^ (((L >> 7) & 7) << 4); };
    auto issueA = [&](int buf, int k0) {
#pragma unroll
        for (int h = 0; h < 2; h++) {
            const int L = (h << 12) + (tid << 4);
            const int Ls = swz(L);
            const int row = Ls >> 7, col = (Ls & 127) >> 1;
            gload_lds16(P + (size_t)(bm + row) * SS + k0 + col, (char*)&As[buf][0] + L);
        }
    };
    auto issueB = [&](int buf, int k0) {
#pragma unroll
        for (int h = 0; h < 4; h++) {
            const int L = (h << 12) + (tid << 4);
            const int Ls = swz(L);
            const int row = Ls >> 7, col = (Ls & 127) >> 1;
            gload_lds16(vt + ((size_t)(bn + row) << 11) + k0 + col, (char*)&Bs[buf][0] + L);
        }
    };

#define PV_TILE(T, CUR, PREF)                                                    \
  {                                                                              \
    s16x8 a[2][2], b[2][4];                                                      \
    _Pragma("unroll")                                                            \
    for (int kx = 0; kx < 2; kx++) {                                             \
      _Pragma("unroll")                                                          \
      for (int m = 0; m < 2; m++)                                                \
        a[kx][m] = *(const s16x8*)((const char*)&As[CUR][0] +                    \
                   swz(((wm + m * 16 + lrow) * 64 + kx * 32 + lk) * 2));         \
      _Pragma("unroll")                                                          \
      for (int n = 0; n < 4; n++)                                                \
        b[kx][n] = *(const s16x8*)((const char*)&Bs[CUR][0] +                    \
                   swz(((wn + n * 16 + lrow) * 64 + kx * 32 + lk) * 2));         \
    }                                                                            \
    if (PREF) { issueB((CUR) ^ 1, ((T) + 1) * 64); SB0;                          \
                issueA((CUR) ^ 1, ((T) + 1) * 64); }                             \
    LGKM0; SB0;                                                                  \
    __builtin_amdgcn_s_setprio(1);                                               \
    _Pragma("unroll")                                                            \
    for (int kx = 0; kx < 2; kx++) {                                             \
      _Pragma("unroll")                                                          \
      for (int m = 0; m < 2; m++) {                                              \
        _Pragma("unroll")                                                        \
        for (int n = 0; n < 4; n++)                                              \
          acc[m][n] = __builtin_amdgcn_mfma_f32_16x16x32_f16(                    \
              as_h(a[kx][m]), as_h(b[kx][n]), acc[m][n], 0, 0, 0);               \
      }                                                                          \
    }                                                                            \
    __builtin_amdgcn_s_setprio(0);                                               \
    if (PREF) { VM0; SB0; }                                                      \
    __builtin_amdgcn_s_barrier();                                                \
  }

    issueB(0, 0); issueA(0, 0);
    VM0;
    __builtin_amdgcn_s_barrier();

    for (int t = 0; t < 32; t += 2) {
        PV_TILE(t,     0, 1);
        PV_TILE(t + 1, 1, (t + 1) < 31);
    }
#undef PV_TILE

#pragma unroll
    for (int m = 0; m < 2; m++) {
#pragma unroll
        for (int n = 0; n < 4; n++) {
#pragma unroll
            for (int j = 0; j < 4; j++) {
                const int row = bm + wm + m * 16 + (lane >> 4) * 4 + j;
                const int col = bn + wn + n * 16 + lrow;
                out[(size_t)row * DD + col] = acc[m][n][j];
            }
        }
    }
}

// merged casts: blocks [0,4096) split x into fp16 hi/lo;
// [4096,7168) transpose W into single fp16 plane.
__global__ __launch_bounds__(256) void cast_all(
    const float* __restrict__ x,
    const float* __restrict__ wq, const float* __restrict__ wk,
    const float* __restrict__ wv,
    short* __restrict__ xh, short* __restrict__ xl,
    short* __restrict__ wt)
{
    const int bid = blockIdx.x;
    if (bid < 4096) {
        const int i = bid * 256 + threadIdx.x;
        const float4 v = ((const float4*)x)[i];
        const float vv[4] = {v.x, v.y, v.z, v.w};
        s16x4 h, l;
#pragma unroll
        for (int j = 0; j < 4; j++) {
            const short hh = f2h(vv[j]);
            h[j] = hh;
            l[j] = f2h(vv[j] - h2f(hh));
        }
        ((s16x4*)xh)[i] = h;
        ((s16x4*)xl)[i] = l;
    } else {
        const int t = (bid - 4096) * 256 + threadIdx.x;
        const int w = t >> 18;
        const int r = t & 262143;
        const float* src = (w == 0) ? wq : ((w == 1) ? wk : wv);
        const float v = src[r];
        const int k = r >> 9, n = r & 511;
        wt[((size_t)w << 18) + ((size_t)n << 9) + k] = f2h(v);
    }
}

// softmax over int16 scores (scale 1/128), fp16 P out
__global__ __launch_bounds__(256) void softmax_rows(
    const short* __restrict__ S, short* __restrict__ P)
{
    const int row = blockIdx.x;
    const long z = blockIdx.y;
    const short* s = S + z * (long)SS * SS + (long)row * SS;
    short* p = P + z * (long)SS * SS + (long)row * SS;
    const int tid = threadIdx.x;

    const s16x8 raw = ((const s16x8*)s)[tid];
    float v[8];
#pragma unroll
    for (int j = 0; j < 8; j++) v[j] = (float)(int)raw[j] * 0.0078125f;

    float m = v[0];
#pragma unroll
    for (int j = 1; j < 8; j++) m = fmaxf(m, v[j]);
#pragma unroll
    for (int off = 32; off >= 1; off >>= 1) m = fmaxf(m, __shfl_xor(m, off));
    __shared__ float redm[4], reds[4];
    if ((tid & 63) == 0) redm[tid >> 6] = m;
    __syncthreads();
    m = fmaxf(fmaxf(redm[0], redm[1]), fmaxf(redm[2], redm[3]));

    float e[8], sum = 0.f;
#pragma unroll
    for (int j = 0; j < 8; j++) { e[j] = __expf(v[j] - m); sum += e[j]; }
#pragma unroll
    for (int off = 32; off >= 1; off >>= 1) sum += __shfl_xor(sum, off);
    if ((tid & 63) == 0) reds[tid >> 6] = sum;
    __syncthreads();
    sum = reds[0] + reds[1] + reds[2] + reds[3];
    const float inv = 1.0f / sum;

    s16x8 o;
#pragma unroll
    for (int j = 0; j < 8; j++) o[j] = f2h(e[j] * inv);
    ((s16x8*)p)[tid] = o;
}

extern "C" void kernel_launch(void* const* d_in, const int* in_sizes, int n_in,
                              void* d_out, int out_size, void* d_ws, size_t ws_size,
                              hipStream_t stream)
{
    const float* x  = (const float*)d_in[0];
    const float* Wq = (const float*)d_in[1];
    const float* Wk = (const float*)d_in[2];
    const float* Wv = (const float*)d_in[3];
    const float* bq = (const float*)d_in[4];
    const float* bk = (const float*)d_in[5];
    const float* bv = (const float*)d_in[6];
    float* out = (float*)d_out;

    const size_t MK = (size_t)BB * SS * DD;
    char* ws = (char*)d_ws;
    short* xh  = (short*)ws; ws += MK * 2;
    short* xl  = (short*)ws; ws += MK * 2;
    short* wt  = (short*)ws; ws += 3ull * DD * DD * 2;
    short* qfp = (short*)ws; ws += MK * 2;
    short* kfp = (short*)ws; ws += MK * 2;
    short* vt  = (short*)ws; ws += MK * 2;
    const size_t fixed = (size_t)(ws - (char*)d_ws);

    int g = 4;
    while (g > 0 && fixed + (size_t)g * ((size_t)SS * SS * 2 + (size_t)SS * SS * 2) > ws_size)
        g >>= 1;
    if (g == 0) return;
    short* sc = (short*)ws;
    short* P  = (short*)(ws + (size_t)g * SS * SS * 2);

    cast_all<<<dim3(7168), 256, 0, stream>>>(x, Wq, Wk, Wv, xh, xl, wt);
    proj_all<<<dim3(12, 64), 256, 0, stream>>>(xh, xl, wt, bq, bk, bv,
                                               qfp, kfp, vt);

    for (int b0 = 0; b0 < BB; b0 += g) {
        const int gg = (b0 + g <= BB) ? g : (BB - b0);
        qkt256<<<dim3(8, 8, gg), 512, 0, stream>>>(
            qfp + (size_t)b0 * SS * DD, kfp + (size_t)b0 * SS * DD, sc, 64 * gg);
        softmax_rows<<<dim3(SS, gg), 256, 0, stream>>>(sc, P);
        pv_gemm<<<dim3(4, 32, gg), 256, 0, stream>>>(
            P, vt + ((size_t)b0 << 20), out + (size_t)b0 * SS * DD);
    }
}

// Round 13
// 107.761 us; speedup vs baseline: 1.0956x; 1.0812x over previous
//
#include <hip/hip_runtime.h>
#include <hip/hip_bf16.h>
#include <hip/hip_fp16.h>

#define BB 4
#define SS 2048
#define DD 512

typedef short s16x8 __attribute__((ext_vector_type(8)));
typedef short s16x4 __attribute__((ext_vector_type(4)));
typedef float f32x4 __attribute__((ext_vector_type(4)));
typedef _Float16 f16x8 __attribute__((ext_vector_type(8)));

__device__ __forceinline__ short f2h(float f) {
    const _Float16 h = (_Float16)f;
    union { _Float16 h; short s; } u; u.h = h; return u.s;
}
__device__ __forceinline__ float h2f(short s) {
    union { short s; _Float16 h; } u; u.s = s; return (float)u.h;
}
__device__ __forceinline__ f16x8 as_h(s16x8 v) {
    union { s16x8 s; f16x8 h; } u; u.s = v; return u.h;
}

__device__ __forceinline__ void gload_lds16(const void* g, void* l) {
    __builtin_amdgcn_global_load_lds(
        (const __attribute__((address_space(1))) void*)g,
        (__attribute__((address_space(3))) void*)l, 16, 0, 0);
}

#define SB0 __builtin_amdgcn_sched_barrier(0)
#define LGKM0 asm volatile("s_waitcnt lgkmcnt(0)" ::: "memory")
#define VM0   asm volatile("s_waitcnt vmcnt(0)" ::: "memory")

// ---------------------------------------------------------------------------
// QK^T 256x256, BK=32, 8 waves, fp16, XCD swizzle, single-phase-per-tile
// (R12). int16 scores (scale 128) via LDS repack.
// ---------------------------------------------------------------------------
__global__ __launch_bounds__(512, 2) void qkt256(
    const short* __restrict__ qf, const short* __restrict__ kf,
    short* __restrict__ outS, int nwg)
{
    __shared__ short lds[65536];

    const int tid = threadIdx.x;
    const int wave = tid >> 6, lane = tid & 63;
    const int flat = blockIdx.x + 8 * blockIdx.y + 64 * blockIdx.z;
    const int w = (flat & 7) * (nwg >> 3) + (flat >> 3);
    const int bm = ((w >> 3) & 7) * 256, bn = (w & 7) * 256;
    const long z = w >> 6;
    qf += z * (long)SS * DD; kf += z * (long)SS * DD;
    outS += z * (long)SS * SS;

    const int wm = (wave >> 2) * 128, wn = (wave & 3) * 64;
    const int lrow = lane & 15, lk16 = (lane >> 4) * 16;

    f32x4 acc[8][4] = {};

    auto base = [&](int buf, int arr) -> short* { return &lds[(buf * 2 + arr) * 8192]; };
    auto issue = [&](int buf, int arr, int k0) {
#pragma unroll
        for (int h = 0; h < 2; h++) {
            const int Lb = (h << 13) + (tid << 4);
            const int Ls = Lb ^ (((Lb >> 7) & 3) << 4);
            const int row = Ls >> 6, elem = (Ls & 63) >> 1;
            const short* s = arr ? kf : qf;
            const int rb = arr ? bn : bm;
            gload_lds16(s + (size_t)(rb + row) * DD + k0 + elem,
                        (char*)base(buf, arr) + Lb);
        }
    };
    auto rd = [&](int buf, int arr, int row) -> s16x8 {
        const int L = (row << 6) + lk16;
        const int Ls = L ^ (((L >> 7) & 3) << 4);
        return *(const s16x8*)((const char*)base(buf, arr) + Ls);
    };

#define QK_TILE(T, CUR, PREF)                                                    \
  {                                                                              \
    s16x8 a[8], b[4];                                                            \
    _Pragma("unroll")                                                            \
    for (int m = 0; m < 8; m++) a[m] = rd(CUR, 0, wm + m * 16 + lrow);           \
    _Pragma("unroll")                                                            \
    for (int n = 0; n < 4; n++) b[n] = rd(CUR, 1, wn + n * 16 + lrow);           \
    if (PREF) { issue((CUR) ^ 1, 1, ((T) + 1) * 32); SB0;                        \
                issue((CUR) ^ 1, 0, ((T) + 1) * 32); }                           \
    LGKM0; SB0;                                                                  \
    __builtin_amdgcn_s_setprio(1);                                               \
    _Pragma("unroll")                                                            \
    for (int m = 0; m < 8; m++) {                                                \
      _Pragma("unroll")                                                          \
      for (int n = 0; n < 4; n++)                                                \
        acc[m][n] = __builtin_amdgcn_mfma_f32_16x16x32_f16(                      \
            as_h(a[m]), as_h(b[n]), acc[m][n], 0, 0, 0);                         \
    }                                                                            \
    __builtin_amdgcn_s_setprio(0);                                               \
    if (PREF) { VM0; SB0; }                                                      \
    __builtin_amdgcn_s_barrier();                                                \
  }

    issue(0, 1, 0); issue(0, 0, 0);
    VM0;
    __builtin_amdgcn_s_barrier();

    for (int t = 0; t < 16; t += 2) {
        QK_TILE(t,     0, 1);
        QK_TILE(t + 1, 1, (t + 1) < 15);
    }
#undef QK_TILE

    __syncthreads();
    short* ebuf = &lds[0];
#pragma unroll
    for (int m = 0; m < 8; m++) {
#pragma unroll
        for (int n = 0; n < 4; n++) {
#pragma unroll
            for (int j = 0; j < 4; j++) {
                const int rl = wm + m * 16 + (lane >> 4) * 4 + j;
                const int cl = wn + n * 16 + lrow;
                const int pcb = (cl >> 3) ^ ((rl & 3) << 1);
                ebuf[rl * 256 + pcb * 8 + (cl & 7)] =
                    (short)__float2int_rn(acc[m][n][j] * 128.0f);
            }
        }
    }
    __syncthreads();
#pragma unroll
    for (int it = 0; it < 16; it++) {
        const int u = it * 512 + tid;
        const int R = u >> 5, cb = u & 31;
        const int pcb = cb ^ ((R & 3) << 1);
        const s16x8 val = *(const s16x8*)&ebuf[R * 256 + pcb * 8];
        *(s16x8*)&outS[(size_t)(bm + R) * SS + bn + cb * 8] = val;
    }
}

// ---------------------------------------------------------------------------
// Unified projection, all-fp16, single-phase-per-tile (R12) + chunked XCD
// swizzle: each XCD owns 8 row-panels x all 12 col-blocks -> per-XCD working
// set 3.5 MB (fits 4 MB L2; was ~37 MB thrash -> FETCH 70 MB).
// ---------------------------------------------------------------------------
__global__ __launch_bounds__(256, 3) void proj_all(
    const short* __restrict__ xh, const short* __restrict__ xl,
    const short* __restrict__ wt,
    const float* __restrict__ bq, const float* __restrict__ bk,
    const float* __restrict__ bv,
    short* __restrict__ qfp, short* __restrict__ kfp, short* __restrict__ vt)
{
    __shared__ short lds[24576];  // [2 buf][3 arr][4096] = 48 KiB; cbuf reuse

    const int tid = threadIdx.x;
    const int wave = tid >> 6, lane = tid & 63;
    const int flat = blockIdx.x + 12 * blockIdx.y;          // 0..767
    const int w = (flat & 7) * 96 + (flat >> 3);            // chunked XCD map
    const int bxi = w % 12, byi = w / 12;
    const int wsel = bxi >> 2;
    const int bnl = (bxi & 3) * 128;
    const int bm = byi * 128;
    const bool lo = (wsel < 2);
    const short* B0 = wt + (size_t)wsel * DD * DD;
    const float* bias = (wsel == 0) ? bq : (wsel == 1) ? bk : bv;

    f32x4 acc[4][4] = {};
    const int wm = (wave >> 1) * 64, wn = (wave & 1) * 64;
    const int lrow = lane & 15, lk16 = (lane >> 4) * 16;

    auto base = [&](int buf, int arr) -> short* { return &lds[(buf * 3 + arr) * 4096]; };
    auto issue = [&](int buf, int arr, int k0) {
#pragma unroll
        for (int h = 0; h < 2; h++) {
            const int Lb = (h << 12) + (tid << 4);
            const int Ls = Lb ^ (((Lb >> 7) & 3) << 4);
            const int row = Ls >> 6, elem = (Ls & 63) >> 1;
            const short* s = (arr == 0) ? xh : (arr == 1) ? xl : B0;
            const int rb = (arr < 2) ? bm : bnl;
            gload_lds16(s + (size_t)(rb + row) * DD + k0 + elem,
                        (char*)base(buf, arr) + Lb);
        }
    };
    auto rd = [&](int buf, int arr, int row) -> s16x8 {
        const int L = (row << 6) + lk16;
        const int Ls = L ^ (((L >> 7) & 3) << 4);
        return *(const s16x8*)((const char*)base(buf, arr) + Ls);
    };

#define PJ_TILE(T, CUR, PREF)                                                    \
  {                                                                              \
    s16x8 ah[4], al[4], b[4];                                                    \
    _Pragma("unroll")                                                            \
    for (int m = 0; m < 4; m++) ah[m] = rd(CUR, 0, wm + m * 16 + lrow);          \
    if (lo) {                                                                    \
      _Pragma("unroll")                                                          \
      for (int m = 0; m < 4; m++) al[m] = rd(CUR, 1, wm + m * 16 + lrow);        \
    }                                                                            \
    _Pragma("unroll")                                                            \
    for (int n = 0; n < 4; n++) b[n] = rd(CUR, 2, wn + n * 16 + lrow);           \
    if (PREF) {                                                                  \
      issue((CUR) ^ 1, 2, ((T) + 1) * 32); SB0;                                  \
      issue((CUR) ^ 1, 0, ((T) + 1) * 32);                                       \
      if (lo) issue((CUR) ^ 1, 1, ((T) + 1) * 32);                               \
    }                                                                            \
    LGKM0; SB0;                                                                  \
    __builtin_amdgcn_s_setprio(1);                                               \
    _Pragma("unroll")                                                            \
    for (int m = 0; m < 4; m++) {                                                \
      _Pragma("unroll")                                                          \
      for (int n = 0; n < 4; n++) {                                              \
        acc[m][n] = __builtin_amdgcn_mfma_f32_16x16x32_f16(                      \
            as_h(ah[m]), as_h(b[n]), acc[m][n], 0, 0, 0);                        \
        if (lo)                                                                  \
          acc[m][n] = __builtin_amdgcn_mfma_f32_16x16x32_f16(                    \
              as_h(al[m]), as_h(b[n]), acc[m][n], 0, 0, 0);                      \
      }                                                                          \
    }                                                                            \
    __builtin_amdgcn_s_setprio(0);                                               \
    if (PREF) { VM0; SB0; }                                                      \
    __builtin_amdgcn_s_barrier();                                                \
  }

    issue(0, 2, 0); issue(0, 0, 0);
    if (lo) issue(0, 1, 0);
    VM0;
    __builtin_amdgcn_s_barrier();

    for (int t = 0; t < 16; t += 2) {
        PJ_TILE(t,     0, 1);
        PJ_TILE(t + 1, 1, (t + 1) < 15);
    }
#undef PJ_TILE

    __syncthreads();
    short* cbuf = &lds[0];  // 32 KiB = 128*128 shorts
#pragma unroll
    for (int m = 0; m < 4; m++) {
#pragma unroll
        for (int n = 0; n < 4; n++) {
#pragma unroll
            for (int j = 0; j < 4; j++) {
                const int rl = wm + m * 16 + (lane >> 4) * 4 + j;
                const int cl = wn + n * 16 + lrow;
                const float v = acc[m][n][j] + bias[bnl + cl];
                if (wsel < 2)
                    cbuf[rl * 128 + (cl ^ ((rl & 7) << 3))] = f2h(v);
                else
                    cbuf[cl * 128 + (rl ^ ((cl & 7) << 3))] = f2h(v);
            }
        }
    }
    __syncthreads();
    if (wsel < 2) {
        short* outp = wsel ? kfp : qfp;
#pragma unroll
        for (int it = 0; it < 8; it++) {
            const int u = it * 256 + tid;
            const int r = u >> 4, c8 = (u & 15) * 8;
            const s16x8 val = *(const s16x8*)&cbuf[r * 128 + (c8 ^ ((r & 7) << 3))];
            *(s16x8*)&outp[(size_t)(bm + r) * DD + bnl + c8] = val;
        }
    } else {
        const int b = bm >> 11, s0 = bm & 2047;
#pragma unroll
        for (int it = 0; it < 8; it++) {
            const int idx = it * 256 + tid;
            const int dd = idx >> 4, c8 = (idx & 15) * 8;
            const s16x8 val = *(const s16x8*)&cbuf[dd * 128 + (c8 ^ ((dd & 7) << 3))];
            *(s16x8*)&vt[((size_t)b << 20) + ((size_t)(bnl + dd) << 11) + s0 + c8] = val;
        }
    }
}

// ---------------------------------------------------------------------------
// PV GEMM fp16: 64x128 tile, BK=64 dbuf, single-phase-per-tile (R12) +
// chunked XCD swizzle (per-XCD: 4 Vt col-panels resident, P streamed once).
// ---------------------------------------------------------------------------
__global__ __launch_bounds__(256, 3) void pv_gemm(
    const short* __restrict__ P, const short* __restrict__ vt,
    float* __restrict__ out, int nwg)
{
    __shared__ short As[2][64 * 64];
    __shared__ short Bs[2][128 * 64];

    const int tid = threadIdx.x;
    const int wave = tid >> 6, lane = tid & 63;
    const int flat = blockIdx.x + 4 * blockIdx.y + 128 * blockIdx.z;
    const int w = (flat & 7) * (nwg >> 3) + (flat >> 3);
    const int bm = ((w >> 2) & 31) * 64, bn = (w & 3) * 128;
    const long z = w >> 7;
    P += z * (long)SS * SS;
    vt += z << 20;
    out += z * (long)SS * DD;

    f32x4 acc[2][4] = {};
    const int wm = (wave >> 1) * 32, wn = (wave & 1) * 64;
    const int lrow = lane & 15, lk = (lane >> 4) * 8;

    auto swz = [](int L) { return L ^ (((L >> 7) & 7) << 4); };
    auto issueA = [&](int buf, int k0) {
#pragma unroll
        for (int h = 0; h < 2; h++) {
            const int L = (h << 12) + (tid << 4);
            const int Ls = swz(L);
            const int row = Ls >> 7, col = (Ls & 127) >> 1;
            gload_lds16(P + (size_t)(bm + row) * SS + k0 + col, (char*)&As[buf][0] + L);
        }
    };
    auto issueB = [&](int buf, int k0) {
#pragma unroll
        for (int h = 0; h < 4; h++) {
            const int L = (h << 12) + (tid << 4);
            const int Ls = swz(L);
            const int row = Ls >> 7, col = (Ls & 127) >> 1;
            gload_lds16(vt + ((size_t)(bn + row) << 11) + k0 + col, (char*)&Bs[buf][0] + L);
        }
    };

#define PV_TILE(T, CUR, PREF)                                                    \
  {                                                                              \
    s16x8 a[2][2], b[2][4];                                                      \
    _Pragma("unroll")                                                            \
    for (int kx = 0; kx < 2; kx++) {                                             \
      _Pragma("unroll")                                                          \
      for (int m = 0; m < 2; m++)                                                \
        a[kx][m] = *(const s16x8*)((const char*)&As[CUR][0] +                    \
                   swz(((wm + m * 16 + lrow) * 64 + kx * 32 + lk) * 2));         \
      _Pragma("unroll")                                                          \
      for (int n = 0; n < 4; n++)                                                \
        b[kx][n] = *(const s16x8*)((const char*)&Bs[CUR][0] +                    \
                   swz(((wn + n * 16 + lrow) * 64 + kx * 32 + lk) * 2));         \
    }                                                                            \
    if (PREF) { issueB((CUR) ^ 1, ((T) + 1) * 64); SB0;                          \
                issueA((CUR) ^ 1, ((T) + 1) * 64); }                             \
    LGKM0; SB0;                                                                  \
    __builtin_amdgcn_s_setprio(1);                                               \
    _Pragma("unroll")                                                            \
    for (int kx = 0; kx < 2; kx++) {                                             \
      _Pragma("unroll")                                                          \
      for (int m = 0; m < 2; m++) {                                              \
        _Pragma("unroll")                                                        \
        for (int n = 0; n < 4; n++)                                              \
          acc[m][n] = __builtin_amdgcn_mfma_f32_16x16x32_f16(                    \
              as_h(a[kx][m]), as_h(b[kx][n]), acc[m][n], 0, 0, 0);               \
      }                                                                          \
    }                                                                            \
    __builtin_amdgcn_s_setprio(0);                                               \
    if (PREF) { VM0; SB0; }                                                      \
    __builtin_amdgcn_s_barrier();                                                \
  }

    issueB(0, 0); issueA(0, 0);
    VM0;
    __builtin_amdgcn_s_barrier();

    for (int t = 0; t < 32; t += 2) {
        PV_TILE(t,     0, 1);
        PV_TILE(t + 1, 1, (t + 1) < 31);
    }
#undef PV_TILE

#pragma unroll
    for (int m = 0; m < 2; m++) {
#pragma unroll
        for (int n = 0; n < 4; n++) {
#pragma unroll
            for (int j = 0; j < 4; j++) {
                const int row = bm + wm + m * 16 + (lane >> 4) * 4 + j;
                const int col = bn + wn + n * 16 + lrow;
                out[(size_t)row * DD + col] = acc[m][n][j];
            }
        }
    }
}

// merged casts: blocks [0,4096) split x into fp16 hi/lo;
// [4096,7168) transpose W into single fp16 plane.
__global__ __launch_bounds__(256) void cast_all(
    const float* __restrict__ x,
    const float* __restrict__ wq, const float* __restrict__ wk,
    const float* __restrict__ wv,
    short* __restrict__ xh, short* __restrict__ xl,
    short* __restrict__ wt)
{
    const int bid = blockIdx.x;
    if (bid < 4096) {
        const int i = bid * 256 + threadIdx.x;
        const float4 v = ((const float4*)x)[i];
        const float vv[4] = {v.x, v.y, v.z, v.w};
        s16x4 h, l;
#pragma unroll
        for (int j = 0; j < 4; j++) {
            const short hh = f2h(vv[j]);
            h[j] = hh;
            l[j] = f2h(vv[j] - h2f(hh));
        }
        ((s16x4*)xh)[i] = h;
        ((s16x4*)xl)[i] = l;
    } else {
        const int t = (bid - 4096) * 256 + threadIdx.x;
        const int w = t >> 18;
        const int r = t & 262143;
        const float* src = (w == 0) ? wq : ((w == 1) ? wk : wv);
        const float v = src[r];
        const int k = r >> 9, n = r & 511;
        wt[((size_t)w << 18) + ((size_t)n << 9) + k] = f2h(v);
    }
}

// softmax over int16 scores (scale 1/128), fp16 P out
__global__ __launch_bounds__(256) void softmax_rows(
    const short* __restrict__ S, short* __restrict__ P)
{
    const int row = blockIdx.x;
    const long z = blockIdx.y;
    const short* s = S + z * (long)SS * SS + (long)row * SS;
    short* p = P + z * (long)SS * SS + (long)row * SS;
    const int tid = threadIdx.x;

    const s16x8 raw = ((const s16x8*)s)[tid];
    float v[8];
#pragma unroll
    for (int j = 0; j < 8; j++) v[j] = (float)(int)raw[j] * 0.0078125f;

    float m = v[0];
#pragma unroll
    for (int j = 1; j < 8; j++) m = fmaxf(m, v[j]);
#pragma unroll
    for (int off = 32; off >= 1; off >>= 1) m = fmaxf(m, __shfl_xor(m, off));
    __shared__ float redm[4], reds[4];
    if ((tid & 63) == 0) redm[tid >> 6] = m;
    __syncthreads();
    m = fmaxf(fmaxf(redm[0], redm[1]), fmaxf(redm[2], redm[3]));

    float e[8], sum = 0.f;
#pragma unroll
    for (int j = 0; j < 8; j++) { e[j] = __expf(v[j] - m); sum += e[j]; }
#pragma unroll
    for (int off = 32; off >= 1; off >>= 1) sum += __shfl_xor(sum, off);
    if ((tid & 63) == 0) reds[tid >> 6] = sum;
    __syncthreads();
    sum = reds[0] + reds[1] + reds[2] + reds[3];
    const float inv = 1.0f / sum;

    s16x8 o;
#pragma unroll
    for (int j = 0; j < 8; j++) o[j] = f2h(e[j] * inv);
    ((s16x8*)p)[tid] = o;
}

extern "C" void kernel_launch(void* const* d_in, const int* in_sizes, int n_in,
                              void* d_out, int out_size, void* d_ws, size_t ws_size,
                              hipStream_t stream)
{
    const float* x  = (const float*)d_in[0];
    const float* Wq = (const float*)d_in[1];
    const float* Wk = (const float*)d_in[2];
    const float* Wv = (const float*)d_in[3];
    const float* bq = (const float*)d_in[4];
    const float* bk = (const float*)d_in[5];
    const float* bv = (const float*)d_in[6];
    float* out = (float*)d_out;

    const size_t MK = (size_t)BB * SS * DD;
    char* ws = (char*)d_ws;
    short* xh  = (short*)ws; ws += MK * 2;
    short* xl  = (short*)ws; ws += MK * 2;
    short* wt  = (short*)ws; ws += 3ull * DD * DD * 2;
    short* qfp = (short*)ws; ws += MK * 2;
    short* kfp = (short*)ws; ws += MK * 2;
    short* vt  = (short*)ws; ws += MK * 2;
    const size_t fixed = (size_t)(ws - (char*)d_ws);

    int g = 4;
    while (g > 0 && fixed + (size_t)g * ((size_t)SS * SS * 2 + (size_t)SS * SS * 2) > ws_size)
        g >>= 1;
    if (g == 0) return;
    short* sc = (short*)ws;
    short* P  = (short*)(ws + (size_t)g * SS * SS * 2);

    cast_all<<<dim3(7168), 256, 0, stream>>>(x, Wq, Wk, Wv, xh, xl, wt);
    proj_all<<<dim3(12, 64), 256, 0, stream>>>(xh, xl, wt, bq, bk, bv,
                                               qfp, kfp, vt);

    for (int b0 = 0; b0 < BB; b0 += g) {
        const int gg = (b0 + g <= BB) ? g : (BB - b0);
        qkt256<<<dim3(8, 8, gg), 512, 0, stream>>>(
            qfp + (size_t)b0 * SS * DD, kfp + (size_t)b0 * SS * DD, sc, 64 * gg);
        softmax_rows<<<dim3(SS, gg), 256, 0, stream>>>(sc, P);
        pv_gemm<<<dim3(4, 32, gg), 256, 0, stream>>>(
            P, vt + ((size_t)b0 << 20), out + (size_t)b0 * SS * DD, 128 * gg);
    }
}